// Round 12
// baseline (992.464 us; speedup 1.0000x reference)
//
#include <hip/hip_runtime.h>

#define BLK 128
#define RSTR 76   // 16B-aligned LDS rows (304B): stride%32=12 -> minimal banking for b128
#define W1OFF (35*512)   // packed-W1 offset (floats) inside wr

// ---------------------------------------------------------------------------
// W3J setup: element-parallel (363 threads), registers-only inner math.
// ---------------------------------------------------------------------------
__device__ __forceinline__ double dfac(int n){
  const double T[8] = {1.0,1.0,2.0,6.0,24.0,120.0,720.0,5040.0};
  return T[n];
}

__device__ __forceinline__ double cgc(int j1,int m1,int j2,int m2,int j3,int m3){
  if (m1+m2 != m3) return 0.0;
  double pre = sqrt((double)(2*j3+1) * dfac(j1+j2-j3)*dfac(j1-j2+j3)*dfac(-j1+j2+j3)/dfac(j1+j2+j3+1));
  pre *= sqrt(dfac(j1+m1)*dfac(j1-m1)*dfac(j2+m2)*dfac(j2-m2)*dfac(j3+m3)*dfac(j3-m3));
  int kmin = 0; if (j2-j3-m1 > kmin) kmin = j2-j3-m1; if (j1-j3+m2 > kmin) kmin = j1-j3+m2;
  int kmax = j1+j2-j3; if (j1-m1 < kmax) kmax = j1-m1; if (j2+m2 < kmax) kmax = j2+m2;
  double s = 0.0;
  for (int k=kmin;k<=kmax;++k){
    double t = 1.0/(dfac(k)*dfac(j1+j2-j3-k)*dfac(j1-m1-k)*dfac(j2+m2-k)*dfac(j3-j2+m1+k)*dfac(j3-j1-m2+k));
    s += (k&1)? -t : t;
  }
  return pre*s;
}

__device__ __forceinline__ void qval(int l, int a, int b, double& qr, double& qi){
  qr = 0.0; qi = 0.0;
  int ma = a - l, mb = b - l;
  if (ma==0){ if (mb==0) qr = 1.0; return; }
  const double is2 = 0.7071067811865476;
  if (ma > 0){
    if (mb == ma)       qr = (ma&1)? -is2 : is2;
    else if (mb == -ma) qr = is2;
  } else {
    int m = -ma;
    if (mb == ma)       qi = is2;
    else if (mb == m)   qi = (m&1)? is2 : -is2;
  }
}

__global__ __launch_bounds__(384) void w3j_kernel(float* __restrict__ w3j){
  __shared__ double Rr[363], Ri[363];
  __shared__ double sInv[11];
  __shared__ int    sFlip[11];
  const int L1t[11] = {0,0,0,1,1,1,1,2,2,2,2};
  const int L2t[11] = {0,1,2,0,1,1,2,0,1,2,2};
  const int L3t[11] = {0,1,2,1,0,2,1,2,1,0,2};
  const int OFFt[12]= {0,1,10,35,44,53,98,143,168,213,238,363};

  int g = threadIdx.x;
  bool act = g < 363;
  int t = 0, l1=0, l2=0, l3=0;
  if (act){
    while (g >= OFFt[t+1]) t++;
    l1=L1t[t]; l2=L2t[t]; l3=L3t[t];
    int n2=2*l2+1, n3=2*l3+1;
    int local = g - OFFt[t];
    int e  = local % n3;
    int tm = local / n3;
    int c  = tm % n2;
    int a  = tm / n2;
    double sr=0.0, si=0.0;
    for (int b=0; b<2*l1+1; b++){
      double q1r,q1i; qval(l1,a,b,q1r,q1i); q1i = -q1i;
      if (q1r==0.0 && q1i==0.0) continue;
      for (int dd=0; dd<n2; dd++){
        double q2r,q2i; qval(l2,c,dd,q2r,q2i); q2i = -q2i;
        if (q2r==0.0 && q2i==0.0) continue;
        double pr = q1r*q2r - q1i*q2i;
        double pi = q1r*q2i + q1i*q2r;
        for (int f=0; f<n3; f++){
          double cg = cgc(l1,b-l1,l2,dd-l2,l3,f-l3);
          if (cg==0.0) continue;
          double q3r,q3i; qval(l3,e,f,q3r,q3i);
          sr += cg*(pr*q3r - pi*q3i);
          si += cg*(pr*q3i + pi*q3r);
        }
      }
    }
    Rr[g]=sr; Ri[g]=si;
  }
  __syncthreads();
  if (threadIdx.x < 11){
    int tt = threadIdx.x;
    int lo = OFFt[tt], hi = OFFt[tt+1];
    double mxr=0.0, mxi=0.0;
    for (int i=lo;i<hi;i++){
      double ar=fabs(Rr[i]), ai=fabs(Ri[i]);
      if (ar>mxr) mxr=ar;
      if (ai>mxi) mxi=ai;
    }
    int flip = (mxi > mxr) ? 1 : 0;
    double nrm=0.0;
    for (int i=lo;i<hi;i++){ double v = flip? Ri[i] : Rr[i]; nrm += v*v; }
    sInv[tt]  = 1.0/sqrt(nrm);
    sFlip[tt] = flip;
  }
  __syncthreads();
  if (act){
    double v = sFlip[t] ? Ri[g] : Rr[g];
    w3j[g] = (float)(v * sInv[t]);
  }
}

// ---------------------------------------------------------------------------
// Node pack: xp[n][35] = fsum diagonal blocks (1x1, 3x3, 5x5)
// ---------------------------------------------------------------------------
__global__ void pack_kernel(const float* __restrict__ x, float* __restrict__ xp, int tot){
  int i = blockIdx.x*256 + threadIdx.x;
  if (i >= tot) return;
  int n = i/35, j = i - n*35;
  int src;
  if (j == 0)       src = 0;
  else if (j < 10){ int r=j-1;  src = (1 + r/3)*9 + 1 + r%3; }
  else            { int r=j-10; src = (4 + r/5)*9 + 4 + r%5; }
  const float* b = x + (size_t)n*162 + src*2;
  xp[i] = b[0] + b[1];
}

// ---------------------------------------------------------------------------
// Weight repack (round-8/9 layout).
// W2 -> per-(path,u) contiguous [64 h][8 w] blocks of 512 floats.
//   s: blk 0..2; p: 3 + p*3+u; d: 15 + p*5+u.
// W1 -> per-channel chunk-major: [16 chunks][10 b][4 j] = 640 floats/channel.
// ---------------------------------------------------------------------------
__global__ void repack_kernel(const float* __restrict__ w2s, const float* __restrict__ w2p,
                              const float* __restrict__ w2d,
                              const float* __restrict__ w1s, const float* __restrict__ w1p,
                              const float* __restrict__ w1d, float* __restrict__ wr){
  int i = blockIdx.x*256 + threadIdx.x;
  int tot2 = 35*512;
  if (i < tot2){
    int blk = i >> 9;
    int idx = i & 511;
    int hc = idx >> 3, w = idx & 7;
    const float* src; int WN, cb, u;
    if (blk < 3){ src=w2s; WN=24; cb=blk*8; u=0; }
    else if (blk < 15){ int b=blk-3; int p=b/3; u=b-p*3; src=w2p; WN=96; const int cbs[4]={0,24,48,72}; cb=cbs[p]; }
    else { int b=blk-15; int p=b/5; u=b-p*5; src=w2d; WN=160; const int cbs[4]={0,40,80,120}; cb=cbs[p]; }
    wr[i] = src[hc*WN + cb + u*8 + w];
  } else if (i < tot2 + 3*640){
    int r = i - tot2;
    int c = r/640; int rem = r - c*640;
    int chunk = rem/40; int idx = rem - chunk*40;
    int b = idx>>2, j = idx&3;
    const float* src = (c==0)? w1s : (c==1)? w1p : w1d;
    wr[i] = src[b*64 + chunk*4 + j];
  }
}

// ---------------------------------------------------------------------------
// CSR build: hist -> scan -> scatter  (sorted by destination node `col`)
// ---------------------------------------------------------------------------
__device__ __forceinline__ bool edge_ok(const float* __restrict__ pos, int row, int col, float mrf){
  float ax = pos[3*row+0]-pos[3*col+0];
  float ay = pos[3*row+1]-pos[3*col+1];
  float az = pos[3*row+2]-pos[3*col+2];
  float d  = sqrtf(fmaf(ax,ax, fmaf(ay,ay, fmaf(az,az, 1e-12f))));
  return d < mrf;
}

__global__ void hist_kernel(const int* __restrict__ ei, const float* __restrict__ pos,
                            const int* __restrict__ mrp, int* __restrict__ cnt, int E){
  int e = blockIdx.x*256 + threadIdx.x;
  if (e >= E) return;
  int row = ei[e], col = ei[E+e];
  if (edge_ok(pos,row,col,(float)mrp[0])) atomicAdd(&cnt[col], 1);
}

__device__ __forceinline__ int wscan(int v, int lane){
  #pragma unroll
  for (int s=1;s<64;s<<=1){
    int t = __shfl_up(v, s);
    if (lane >= s) v += t;
  }
  return v;
}

__global__ void scan_kernel(int* __restrict__ cnt, int* __restrict__ off, int N){
  __shared__ int wsum[16];
  __shared__ int srun;
  int t=threadIdx.x, lane=t&63, w=t>>6;
  if (t==0) srun=0;
  __syncthreads();
  for (int base=0; base<N; base+=1024){
    int v = (base+t<N) ? cnt[base+t] : 0;
    int incl = wscan(v, lane);
    if (lane==63) wsum[w]=incl;
    __syncthreads();
    int run = srun;
    int woff = 0;
    for (int i=0;i<w;i++) woff += wsum[i];
    int ex = run + woff + incl - v;
    if (base+t<N){ off[base+t]=ex; cnt[base+t]=ex; }
    __syncthreads();
    if (t==1023) srun = run + woff + incl;
    __syncthreads();
  }
  if (t==0) off[N]=srun;
}

__global__ void scatter_kernel(const int* __restrict__ ei, const float* __restrict__ pos,
                               const int* __restrict__ mrp, int* __restrict__ cursor,
                               int* __restrict__ csrR, int* __restrict__ csrC, int E){
  int e = blockIdx.x*256 + threadIdx.x;
  if (e >= E) return;
  int row = ei[e], col = ei[E+e];
  if (edge_ok(pos,row,col,(float)mrp[0])){
    int s = atomicAdd(&cursor[col], 1);
    csrR[s] = row;
    csrC[s] = col;
  }
}

// ---------------------------------------------------------------------------
// Edge compute helpers.  h in LDS; weights via per-lane (vmcnt) vector loads.
// All fmaf chain orders bit-identical to rounds 8/9.
// ---------------------------------------------------------------------------
// Packed-W1 compute_h: per chunk one contiguous 160B row; round-9 order.
__device__ __forceinline__ void compute_h(const float (&emb)[10], const float* __restrict__ w1r, float* hrow){
  const float RS10 = 0.31622776601683794f;  // 1/sqrt(10)
  #pragma unroll 2
  for (int i=0; i<16; ++i){
    const float* r = w1r + i*40;
    float a0=0.f,a1=0.f,a2=0.f,a3=0.f;
    #pragma unroll
    for (int b=0;b<10;b++){
      a0 = fmaf(emb[b], r[b*4+0], a0);
      a1 = fmaf(emb[b], r[b*4+1], a1);
      a2 = fmaf(emb[b], r[b*4+2], a2);
      a3 = fmaf(emb[b], r[b*4+3], a3);
    }
    float4 hv;
    hv.x = fmaxf(a0*RS10, 0.f);
    hv.y = fmaxf(a1*RS10, 0.f);
    hv.z = fmaxf(a2*RS10, 0.f);
    hv.w = fmaxf(a3*RS10, 0.f);
    *reinterpret_cast<float4*>(hrow+i*4) = hv;
  }
}

// Raw-W1 compute_h (fallback kernel only).
__device__ __forceinline__ void compute_h_raw(const float (&emb)[10], const float* __restrict__ w1, float* hrow){
  const float RS10 = 0.31622776601683794f;
  #pragma unroll 1
  for (int hh=0; hh<64; hh+=4){
    float a0=0.f,a1=0.f,a2=0.f,a3=0.f;
    #pragma unroll
    for (int b=0;b<10;b++){
      const float* r = w1 + b*64 + hh;
      a0 = fmaf(emb[b], r[0], a0);
      a1 = fmaf(emb[b], r[1], a1);
      a2 = fmaf(emb[b], r[2], a2);
      a3 = fmaf(emb[b], r[3], a3);
    }
    float4 hv;
    hv.x = fmaxf(a0*RS10, 0.f);
    hv.y = fmaxf(a1*RS10, 0.f);
    hv.z = fmaxf(a2*RS10, 0.f);
    hv.w = fmaxf(a3*RS10, 0.f);
    *reinterpret_cast<float4*>(hrow+hh) = hv;
  }
}

// s[k] = CP * sum_{i,j} x1[i]*sh[j]*W3J[i,j,k]
template<int L1, int L2, int L3, int W3JOFF>
__device__ __forceinline__ void calc_s(const float* __restrict__ w3j,
    const float (&x1)[2*L1+1], const float (&sh1)[3], const float (&sh2)[5],
    float CP, float (&s)[2*L3+1])
{
  constexpr int N1=2*L1+1, N2=2*L2+1, N3=2*L3+1;
  #pragma unroll
  for (int k=0;k<N3;k++) s[k]=0.f;
  #pragma unroll
  for (int i=0;i<N1;i++){
    #pragma unroll
    for (int j=0;j<N2;j++){
      float shv = (L2==0) ? 1.0f : ((L2==1) ? sh1[j] : sh2[j]);
      float c = x1[i]*shv;
      #pragma unroll
      for (int k=0;k<N3;k++)
        s[k] = fmaf(c, w3j[W3JOFF + (i*N2+j)*N3 + k], s[k]);
    }
  }
  #pragma unroll
  for (int k=0;k<N3;k++) s[k] *= CP;
}

// Merged wg pass over REPACKED weights, addresses per-lane (vector loads ->
// vmcnt), h via ds_read_b128 (lgkmcnt) -> the two streams decouple.
template<int P>
__device__ __forceinline__ void wg_pass_r(const float* __restrict__ wr,
    const int (&blks)[P], const float* __restrict__ hrow, float (&wg)[P][8])
{
  #pragma unroll
  for (int p=0;p<P;p++)
    #pragma unroll
    for (int w=0;w<8;w++) wg[p][w]=0.f;
  #pragma unroll 1
  for (int hc=0;hc<64;hc+=4){
    float4 hv = *reinterpret_cast<const float4*>(hrow+hc);
    #pragma unroll
    for (int p=0;p<P;p++){
      const float* r0 = wr + blks[p]*512 + hc*8;
      #pragma unroll
      for (int w=0;w<8;w++){
        float t0 = fmaf(hv.x, r0[w],    wg[p][w]);
        t0       = fmaf(hv.y, r0[8+w],  t0);
        t0       = fmaf(hv.z, r0[16+w], t0);
        wg[p][w] = fmaf(hv.w, r0[24+w], t0);
      }
    }
  }
}

// Legacy merged wg pass over raw W2 (fallback kernel only).
template<int P, int WN>
__device__ __forceinline__ void wg_pass(const float* __restrict__ w2,
    const int (&cb)[P], int u8, const float* __restrict__ hrow, float (&wg)[P][8])
{
  #pragma unroll
  for (int p=0;p<P;p++)
    #pragma unroll
    for (int w=0;w<8;w++) wg[p][w]=0.f;
  #pragma unroll 1
  for (int hc=0;hc<64;hc+=4){
    float4 hv = *reinterpret_cast<const float4*>(hrow+hc);
    #pragma unroll
    for (int p=0;p<P;p++){
      const float* r0 = w2 + cb[p] + u8 + hc*WN;
      #pragma unroll
      for (int w=0;w<8;w++){
        float t0 = fmaf(hv.x, r0[w],      wg[p][w]);
        t0       = fmaf(hv.y, r0[WN+w],   t0);
        t0       = fmaf(hv.z, r0[2*WN+w], t0);
        wg[p][w] = fmaf(hv.w, r0[3*WN+w], t0);
      }
    }
  }
}

template<int N3, int OUTB>
__device__ __forceinline__ void acc_o(const float (&wgp)[8], const float (&s)[N3], float (&o)[72]){
  #pragma unroll
  for (int w=0;w<8;w++){
    #pragma unroll
    for (int k=0;k<N3;k++)
      o[OUTB + w*N3 + k] = fmaf(wgp[w], s[k], o[OUTB + w*N3 + k]);
  }
}

// ---------------------------------------------------------------------------
// CSR edge kernel: one thread per CSR slot; block-wide segmented reduction.
// ---------------------------------------------------------------------------
template<bool PACKED>
__global__ __launch_bounds__(BLK) void edge_kernel_csr(
  const int* __restrict__ csrR, const int* __restrict__ csrC,
  const int* __restrict__ off, int N,
  const float* __restrict__ pos, const float* __restrict__ x, const float* __restrict__ xp,
  const float* __restrict__ w3j, const int* __restrict__ mrp,
  const float* __restrict__ wr,
  float* __restrict__ out, float rs)
{
  __shared__ __align__(16) float hb[BLK*RSTR];  // per-thread h row / o staging
  __shared__ int scol[BLK];
  __shared__ int lmeta[BLK];   // s0 | len<<8 | comp<<31
  __shared__ int lcount;

  int tid = threadIdx.x;
  int blockBase = blockIdx.x*BLK;
  int Ev = off[N];
  if (blockBase >= Ev) return;
  int slot = blockBase + tid;
  bool valid = slot < Ev;
  int row = valid ? csrR[slot] : 0;
  int key = valid ? csrC[slot] : -1;
  int colIdx = valid ? key : 0;

  scol[tid] = key;
  if (tid==0) lcount = 0;
  __syncthreads();
  if (valid && (tid==0 || scol[tid-1]!=key)){
    int len=1;
    while (tid+len<BLK && scol[tid+len]==key) len++;
    int comp = (off[key] >= blockBase) && (off[key+1] <= blockBase+BLK);
    int idx = atomicAdd(&lcount, 1);
    lmeta[idx] = tid | (len<<8) | (comp<<31);
  }
  __syncthreads();
  int lc = lcount;

  // ---- geometry + radial embedding ----
  // Invalid lanes use row=col=0 -> d~1e-6 -> emb underflows to exactly 0 -> o = 0.
  float ax = pos[3*row+0]-pos[3*colIdx+0];
  float ay = pos[3*row+1]-pos[3*colIdx+1];
  float az = pos[3*row+2]-pos[3*colIdx+2];
  float d  = sqrtf(fmaf(ax,ax, fmaf(ay,ay, fmaf(az,az, 1e-12f))));
  float mrf = (float)mrp[0];
  float inv = 1.0f/d;
  float ux=ax*inv, uy=ay*inv, uz=az*inv;
  float sh1[3] = {1.7320508075688772f*uy, 1.7320508075688772f*uz, 1.7320508075688772f*ux};
  float sh2[5] = {3.872983346207417f*ux*uy, 3.872983346207417f*uy*uz,
                  1.118033988749895f*(3.f*uz*uz-1.f), 3.872983346207417f*ux*uz,
                  1.9364916731037085f*(ux*ux-uy*uy)};
  float emb[10];
  {
    float xs = d * (11.0f/mrf);
    float CE = 1.14136f * expf(2.0f) * sqrtf(10.0f);
    #pragma unroll
    for (int b=0;b<10;b++){
      float t1 = xs - (float)b;
      float t2 = (float)(b+2) - xs;
      float s1 = (t1>0.f)? expf(-1.0f/t1) : 0.f;
      float s2 = (t2>0.f)? expf(-1.0f/t2) : 0.f;
      emb[b] = CE*s1*s2;
    }
  }

  // Opaque per-lane zero: forces weight addresses into VGPRs -> vector loads
  // (vmcnt), decoupled from the LDS h-reads (lgkmcnt).
  int zoff;
  asm volatile("v_mov_b32 %0, 0" : "=v"(zoff));
  const float* wrv = wr + zoff;
  const float* w1r = wr + W1OFF + zoff;

  float* hrow = &hb[tid*RSTR];
  const float* xrow = PACKED ? (xp + (size_t)row*35) : (x + (size_t)row*162);

  auto flush_reduce = [&](const float (&o)[72], int PO){
    #pragma unroll
    for (int i=0;i<72;i+=4){
      float4 v; v.x=o[i]; v.y=o[i+1]; v.z=o[i+2]; v.w=o[i+3];
      *reinterpret_cast<float4*>(hrow+i) = v;
    }
    __syncthreads();
    int total = lc*72;
    for (int task = tid; task < total; task += BLK){
      int li = task/72;
      int el = task - li*72;
      int meta = lmeta[li];
      int s0  = meta & 255;
      int len = (meta>>8) & 255;
      int c   = scol[s0];
      float sum = 0.f;
      const float* p = &hb[s0*RSTR + el];
      for (int i=0;i<len;i++) sum += p[i*RSTR];
      float* dst = out + (size_t)c*216 + PO + el;
      if (meta < 0) *dst = sum;            // comp bit set: unique writer
      else unsafeAtomicAdd(dst, sum);      // block-boundary segment
    }
    __syncthreads();
  };

  // ---- l1 = 0 (s channel): 3 paths, one wg sweep ----
  {
    compute_h(emb, w1r + 0, hrow);
    float o[72];
    #pragma unroll
    for (int i=0;i<72;i++) o[i]=0.f;
    float x1[1];
    x1[0] = PACKED ? xrow[0] : (xrow[0]+xrow[1]);
    float sA[1], sB[3], sC[5];
    calc_s<0,0,0,  0>(w3j,x1,sh1,sh2, 0.17677669529663687f*rs, sA);
    calc_s<0,1,1,  1>(w3j,x1,sh1,sh2, 0.30618621784789724f*rs, sB);
    calc_s<0,2,2, 10>(w3j,x1,sh1,sh2, 0.39528470752104744f*rs, sC);
    float wg[3][8];
    const int blks[3] = {0,1,2};
    wg_pass_r<3>(wrv, blks, hrow, wg);
    acc_o<1, 0>(wg[0], sA, o);
    acc_o<3, 8>(wg[1], sB, o);
    acc_o<5,32>(wg[2], sC, o);
    flush_reduce(o, 0);
  }
  // ---- l1 = 1 (p channel): 4 paths, one wg sweep per u ----
  {
    compute_h(emb, w1r + 640, hrow);
    float o[72];
    #pragma unroll
    for (int i=0;i<72;i++) o[i]=0.f;
    #pragma unroll 1
    for (int u=0;u<3;++u){
      float x1[3];
      #pragma unroll
      for (int i=0;i<3;i++){
        int src = ((1+u)*9 + 1+i)*2;
        x1[i] = PACKED ? xrow[1+u*3+i] : (xrow[src]+xrow[src+1]);
      }
      float sA[3], sB[1], sC[5], sD[3];
      calc_s<1,0,1, 35>(w3j,x1,sh1,sh2, 0.125f*rs,               sA);
      calc_s<1,1,0, 44>(w3j,x1,sh1,sh2, 0.10206207261596577f*rs, sB);
      calc_s<1,1,2, 53>(w3j,x1,sh1,sh2, 0.22821773229381923f*rs, sC);
      calc_s<1,2,1, 98>(w3j,x1,sh1,sh2, 0.125f*rs,               sD);
      float wg[4][8];
      const int blks[4] = {3+u, 6+u, 9+u, 12+u};
      wg_pass_r<4>(wrv, blks, hrow, wg);
      acc_o<3, 8>(wg[0], sA, o);
      acc_o<1, 0>(wg[1], sB, o);
      acc_o<5,32>(wg[2], sC, o);
      acc_o<3, 8>(wg[3], sD, o);
    }
    flush_reduce(o, 72);
  }
  // ---- l1 = 2 (d channel): 4 paths, one wg sweep per u ----
  {
    compute_h(emb, w1r + 1280, hrow);
    float o[72];
    #pragma unroll
    for (int i=0;i<72;i++) o[i]=0.f;
    #pragma unroll 1
    for (int u=0;u<5;++u){
      float x1[5];
      #pragma unroll
      for (int i=0;i<5;i++){
        int src = ((4+u)*9 + 4+i)*2;
        x1[i] = PACKED ? xrow[10+u*5+i] : (xrow[src]+xrow[src+1]);
      }
      float sA[5], sB[3], sC[1], sD[5];
      calc_s<2,0,2,143>(w3j,x1,sh1,sh2, 0.125f*rs,               sA);
      calc_s<2,1,1,168>(w3j,x1,sh1,sh2, 0.13693063937629152f*rs, sB);
      calc_s<2,2,0,213>(w3j,x1,sh1,sh2, 0.07905694150420948f*rs, sC);
      calc_s<2,2,2,238>(w3j,x1,sh1,sh2, 0.125f*rs,               sD);
      float wg[4][8];
      const int blks[4] = {15+u, 20+u, 25+u, 30+u};
      wg_pass_r<4>(wrv, blks, hrow, wg);
      acc_o<5,32>(wg[0], sA, o);
      acc_o<3, 8>(wg[1], sB, o);
      acc_o<1, 0>(wg[2], sC, o);
      acc_o<5,32>(wg[3], sD, o);
    }
    flush_reduce(o, 144);
  }
}

// ---------------------------------------------------------------------------
// Tier-C fallback: atomic kernel over raw W1/W2 (used only if workspace tiny)
// ---------------------------------------------------------------------------
__device__ __forceinline__ void flush72(const float (&o)[72], float* dst){
  #pragma unroll
  for (int i=0;i<72;i++) unsafeAtomicAdd(dst+i, o[i]);
}

__global__ __launch_bounds__(BLK) void edge_kernel_atomic(
  const int* __restrict__ ei, const float* __restrict__ pos,
  const float* __restrict__ x,
  const float* __restrict__ w3j, const int* __restrict__ mrp,
  const float* __restrict__ w1s, const float* __restrict__ w2s,
  const float* __restrict__ w1p, const float* __restrict__ w2p,
  const float* __restrict__ w1d, const float* __restrict__ w2d,
  float* __restrict__ out, int E, float rs)
{
  __shared__ __align__(16) float hbA[BLK*RSTR];
  int e = blockIdx.x*BLK + threadIdx.x;
  if (e >= E) return;
  int row = ei[e], col = ei[E+e];
  float ax = pos[3*row+0]-pos[3*col+0];
  float ay = pos[3*row+1]-pos[3*col+1];
  float az = pos[3*row+2]-pos[3*col+2];
  float d  = sqrtf(fmaf(ax,ax, fmaf(ay,ay, fmaf(az,az, 1e-12f))));
  float mrf = (float)mrp[0];
  if (d >= mrf) return;
  float inv = 1.0f/d;
  float ux=ax*inv, uy=ay*inv, uz=az*inv;
  float sh1[3] = {1.7320508075688772f*uy, 1.7320508075688772f*uz, 1.7320508075688772f*ux};
  float sh2[5] = {3.872983346207417f*ux*uy, 3.872983346207417f*uy*uz,
                  1.118033988749895f*(3.f*uz*uz-1.f), 3.872983346207417f*ux*uz,
                  1.9364916731037085f*(ux*ux-uy*uy)};
  float emb[10];
  {
    float xs = d * (11.0f/mrf);
    float CE = 1.14136f * expf(2.0f) * sqrtf(10.0f);
    #pragma unroll
    for (int b=0;b<10;b++){
      float t1 = xs - (float)b;
      float t2 = (float)(b+2) - xs;
      float s1 = (t1>0.f)? expf(-1.0f/t1) : 0.f;
      float s2 = (t2>0.f)? expf(-1.0f/t2) : 0.f;
      emb[b] = CE*s1*s2;
    }
  }
  float* hrow = &hbA[threadIdx.x*RSTR];
  const float* xrow = x + (size_t)row*162;
  float* obase = out + (size_t)col*216;
  {
    compute_h_raw(emb, w1s, hrow);
    float o[72];
    #pragma unroll
    for (int i=0;i<72;i++) o[i]=0.f;
    float x1[1] = { xrow[0]+xrow[1] };
    float sA[1], sB[3], sC[5];
    calc_s<0,0,0,  0>(w3j,x1,sh1,sh2, 0.17677669529663687f*rs, sA);
    calc_s<0,1,1,  1>(w3j,x1,sh1,sh2, 0.30618621784789724f*rs, sB);
    calc_s<0,2,2, 10>(w3j,x1,sh1,sh2, 0.39528470752104744f*rs, sC);
    float wg[3][8];
    const int cb[3] = {0,8,16};
    wg_pass<3,24>(w2s, cb, 0, hrow, wg);
    acc_o<1, 0>(wg[0], sA, o);
    acc_o<3, 8>(wg[1], sB, o);
    acc_o<5,32>(wg[2], sC, o);
    flush72(o, obase);
  }
  {
    compute_h_raw(emb, w1p, hrow);
    float o[72];
    #pragma unroll
    for (int i=0;i<72;i++) o[i]=0.f;
    #pragma unroll 1
    for (int u=0;u<3;++u){
      float x1[3];
      #pragma unroll
      for (int i=0;i<3;i++){ int src = ((1+u)*9 + 1+i)*2; x1[i] = xrow[src]+xrow[src+1]; }
      float sA[3], sB[1], sC[5], sD[3];
      calc_s<1,0,1, 35>(w3j,x1,sh1,sh2, 0.125f*rs,               sA);
      calc_s<1,1,0, 44>(w3j,x1,sh1,sh2, 0.10206207261596577f*rs, sB);
      calc_s<1,1,2, 53>(w3j,x1,sh1,sh2, 0.22821773229381923f*rs, sC);
      calc_s<1,2,1, 98>(w3j,x1,sh1,sh2, 0.125f*rs,               sD);
      float wg[4][8];
      const int cb[4] = {0,24,48,72};
      wg_pass<4,96>(w2p, cb, u*8, hrow, wg);
      acc_o<3, 8>(wg[0], sA, o);
      acc_o<1, 0>(wg[1], sB, o);
      acc_o<5,32>(wg[2], sC, o);
      acc_o<3, 8>(wg[3], sD, o);
    }
    flush72(o, obase + 72);
  }
  {
    compute_h_raw(emb, w1d, hrow);
    float o[72];
    #pragma unroll
    for (int i=0;i<72;i++) o[i]=0.f;
    #pragma unroll 1
    for (int u=0;u<5;++u){
      float x1[5];
      #pragma unroll
      for (int i=0;i<5;i++){ int src = ((4+u)*9 + 4+i)*2; x1[i] = xrow[src]+xrow[src+1]; }
      float sA[5], sB[3], sC[1], sD[5];
      calc_s<2,0,2,143>(w3j,x1,sh1,sh2, 0.125f*rs,               sA);
      calc_s<2,1,1,168>(w3j,x1,sh1,sh2, 0.13693063937629152f*rs, sB);
      calc_s<2,2,0,213>(w3j,x1,sh1,sh2, 0.07905694150420948f*rs, sC);
      calc_s<2,2,2,238>(w3j,x1,sh1,sh2, 0.125f*rs,               sD);
      float wg[4][8];
      const int cb[4] = {0,40,80,120};
      wg_pass<4,160>(w2d, cb, u*8, hrow, wg);
      acc_o<5,32>(wg[0], sA, o);
      acc_o<3, 8>(wg[1], sB, o);
      acc_o<1, 0>(wg[2], sC, o);
      acc_o<5,32>(wg[3], sD, o);
    }
    flush72(o, obase + 144);
  }
}

// ---------------------------------------------------------------------------
extern "C" void kernel_launch(void* const* d_in, const int* in_sizes, int n_in,
                              void* d_out, int out_size, void* d_ws, size_t ws_size,
                              hipStream_t stream){
  (void)n_in; (void)out_size;
  const float* x   = (const float*)d_in[0];
  const int*   ei  = (const int*)  d_in[1];
  const float* pos = (const float*)d_in[2];
  const int*   mr  = (const int*)  d_in[3];
  const float* w1s = (const float*)d_in[5];
  const float* w2s = (const float*)d_in[6];
  const float* w1p = (const float*)d_in[7];
  const float* w2p = (const float*)d_in[8];
  const float* w1d = (const float*)d_in[9];
  const float* w2d = (const float*)d_in[10];

  int N = in_sizes[0]/162;
  int E = in_sizes[1]/2;
  float rs = sqrtf((float)N/(float)E);

  auto alignup = [](size_t v){ return (v + 255) & ~(size_t)255; };
  size_t o_off  = 0;
  size_t o_cnt  = alignup(o_off + (size_t)(N+1)*4);
  size_t o_csrR = alignup(o_cnt + (size_t)N*4);
  size_t o_csrC = alignup(o_csrR + (size_t)E*4);
  size_t o_w3j  = alignup(o_csrC + (size_t)E*4);
  size_t o_wr   = alignup(o_w3j + 2048);
  size_t o_xp   = alignup(o_wr + (size_t)(35*512 + 3*640)*4);
  size_t needB  = o_xp;
  size_t needA  = o_xp + (size_t)N*35*4;

  char* wsb = (char*)d_ws;
  hipMemsetAsync(d_out, 0, (size_t)N*216*sizeof(float), stream);

  if (ws_size >= needB){
    int*   off  = (int*)(wsb + o_off);
    int*   cnt  = (int*)(wsb + o_cnt);
    int*   csrR = (int*)(wsb + o_csrR);
    int*   csrC = (int*)(wsb + o_csrC);
    float* w3j  = (float*)(wsb + o_w3j);
    float* wr   = (float*)(wsb + o_wr);
    float* xp   = (float*)(wsb + o_xp);

    hipMemsetAsync(cnt, 0, (size_t)N*4, stream);
    w3j_kernel<<<1,384,0,stream>>>(w3j);
    int rtot = 35*512 + 3*640;
    repack_kernel<<<(rtot+255)/256,256,0,stream>>>(w2s, w2p, w2d, w1s, w1p, w1d, wr);
    hist_kernel<<<(E+255)/256,256,0,stream>>>(ei, pos, mr, cnt, E);
    scan_kernel<<<1,1024,0,stream>>>(cnt, off, N);
    scatter_kernel<<<(E+255)/256,256,0,stream>>>(ei, pos, mr, cnt, csrR, csrC, E);

    int nblk = (E + BLK - 1)/BLK;
    if (ws_size >= needA){
      int tot = N*35;
      pack_kernel<<<(tot+255)/256,256,0,stream>>>(x, xp, tot);
      edge_kernel_csr<true><<<nblk, BLK, 0, stream>>>(
        csrR, csrC, off, N, pos, x, xp, w3j, mr, wr, (float*)d_out, rs);
    } else {
      edge_kernel_csr<false><<<nblk, BLK, 0, stream>>>(
        csrR, csrC, off, N, pos, x, x, w3j, mr, wr, (float*)d_out, rs);
    }
  } else {
    float* w3j = (float*)wsb;
    w3j_kernel<<<1,384,0,stream>>>(w3j);
    edge_kernel_atomic<<<(E+BLK-1)/BLK, BLK, 0, stream>>>(
      ei, pos, x, w3j, mr, w1s, w2s, w1p, w2p, w1d, w2d, (float*)d_out, E, rs);
  }
}

// Round 13
// 586.666 us; speedup vs baseline: 1.6917x; 1.6917x over previous
//
#include <hip/hip_runtime.h>

#define BLK 128
#define RSTR 76   // 16B-aligned LDS rows (304B): ds_*_b128 for h/o staging
#define W1OFF (35*512)   // packed-W1 offset (floats) inside wr

// ---------------------------------------------------------------------------
// W3J setup: element-parallel (363 threads), registers-only inner math.
// ---------------------------------------------------------------------------
__device__ __forceinline__ double dfac(int n){
  const double T[8] = {1.0,1.0,2.0,6.0,24.0,120.0,720.0,5040.0};
  return T[n];
}

__device__ __forceinline__ double cgc(int j1,int m1,int j2,int m2,int j3,int m3){
  if (m1+m2 != m3) return 0.0;
  double pre = sqrt((double)(2*j3+1) * dfac(j1+j2-j3)*dfac(j1-j2+j3)*dfac(-j1+j2+j3)/dfac(j1+j2+j3+1));
  pre *= sqrt(dfac(j1+m1)*dfac(j1-m1)*dfac(j2+m2)*dfac(j2-m2)*dfac(j3+m3)*dfac(j3-m3));
  int kmin = 0; if (j2-j3-m1 > kmin) kmin = j2-j3-m1; if (j1-j3+m2 > kmin) kmin = j1-j3+m2;
  int kmax = j1+j2-j3; if (j1-m1 < kmax) kmax = j1-m1; if (j2+m2 < kmax) kmax = j2+m2;
  double s = 0.0;
  for (int k=kmin;k<=kmax;++k){
    double t = 1.0/(dfac(k)*dfac(j1+j2-j3-k)*dfac(j1-m1-k)*dfac(j2+m2-k)*dfac(j3-j2+m1+k)*dfac(j3-j1-m2+k));
    s += (k&1)? -t : t;
  }
  return pre*s;
}

__device__ __forceinline__ void qval(int l, int a, int b, double& qr, double& qi){
  qr = 0.0; qi = 0.0;
  int ma = a - l, mb = b - l;
  if (ma==0){ if (mb==0) qr = 1.0; return; }
  const double is2 = 0.7071067811865476;
  if (ma > 0){
    if (mb == ma)       qr = (ma&1)? -is2 : is2;
    else if (mb == -ma) qr = is2;
  } else {
    int m = -ma;
    if (mb == ma)       qi = is2;
    else if (mb == m)   qi = (m&1)? is2 : -is2;
  }
}

__global__ __launch_bounds__(384) void w3j_kernel(float* __restrict__ w3j){
  __shared__ double Rr[363], Ri[363];
  __shared__ double sInv[11];
  __shared__ int    sFlip[11];
  const int L1t[11] = {0,0,0,1,1,1,1,2,2,2,2};
  const int L2t[11] = {0,1,2,0,1,1,2,0,1,2,2};
  const int L3t[11] = {0,1,2,1,0,2,1,2,1,0,2};
  const int OFFt[12]= {0,1,10,35,44,53,98,143,168,213,238,363};

  int g = threadIdx.x;
  bool act = g < 363;
  int t = 0, l1=0, l2=0, l3=0;
  if (act){
    while (g >= OFFt[t+1]) t++;
    l1=L1t[t]; l2=L2t[t]; l3=L3t[t];
    int n2=2*l2+1, n3=2*l3+1;
    int local = g - OFFt[t];
    int e  = local % n3;
    int tm = local / n3;
    int c  = tm % n2;
    int a  = tm / n2;
    double sr=0.0, si=0.0;
    for (int b=0; b<2*l1+1; b++){
      double q1r,q1i; qval(l1,a,b,q1r,q1i); q1i = -q1i;
      if (q1r==0.0 && q1i==0.0) continue;
      for (int dd=0; dd<n2; dd++){
        double q2r,q2i; qval(l2,c,dd,q2r,q2i); q2i = -q2i;
        if (q2r==0.0 && q2i==0.0) continue;
        double pr = q1r*q2r - q1i*q2i;
        double pi = q1r*q2i + q1i*q2r;
        for (int f=0; f<n3; f++){
          double cg = cgc(l1,b-l1,l2,dd-l2,l3,f-l3);
          if (cg==0.0) continue;
          double q3r,q3i; qval(l3,e,f,q3r,q3i);
          sr += cg*(pr*q3r - pi*q3i);
          si += cg*(pr*q3i + pi*q3r);
        }
      }
    }
    Rr[g]=sr; Ri[g]=si;
  }
  __syncthreads();
  if (threadIdx.x < 11){
    int tt = threadIdx.x;
    int lo = OFFt[tt], hi = OFFt[tt+1];
    double mxr=0.0, mxi=0.0;
    for (int i=lo;i<hi;i++){
      double ar=fabs(Rr[i]), ai=fabs(Ri[i]);
      if (ar>mxr) mxr=ar;
      if (ai>mxi) mxi=ai;
    }
    int flip = (mxi > mxr) ? 1 : 0;
    double nrm=0.0;
    for (int i=lo;i<hi;i++){ double v = flip? Ri[i] : Rr[i]; nrm += v*v; }
    sInv[tt]  = 1.0/sqrt(nrm);
    sFlip[tt] = flip;
  }
  __syncthreads();
  if (act){
    double v = sFlip[t] ? Ri[g] : Rr[g];
    w3j[g] = (float)(v * sInv[t]);
  }
}

// ---------------------------------------------------------------------------
// Node pack: xp[n][35] = fsum diagonal blocks (1x1, 3x3, 5x5)
// ---------------------------------------------------------------------------
__global__ void pack_kernel(const float* __restrict__ x, float* __restrict__ xp, int tot){
  int i = blockIdx.x*256 + threadIdx.x;
  if (i >= tot) return;
  int n = i/35, j = i - n*35;
  int src;
  if (j == 0)       src = 0;
  else if (j < 10){ int r=j-1;  src = (1 + r/3)*9 + 1 + r%3; }
  else            { int r=j-10; src = (4 + r/5)*9 + 4 + r%5; }
  const float* b = x + (size_t)n*162 + src*2;
  xp[i] = b[0] + b[1];
}

// ---------------------------------------------------------------------------
// Weight repack (round-8/9 layout).
// W2 -> per-(path,u) contiguous [64 h][8 w] blocks of 512 floats.
//   s: blk 0..2; p: 3 + p*3+u; d: 15 + p*5+u.
// W1 -> per-channel chunk-major: [16 chunks][10 b][4 j] = 640 floats/channel.
// ---------------------------------------------------------------------------
__global__ void repack_kernel(const float* __restrict__ w2s, const float* __restrict__ w2p,
                              const float* __restrict__ w2d,
                              const float* __restrict__ w1s, const float* __restrict__ w1p,
                              const float* __restrict__ w1d, float* __restrict__ wr){
  int i = blockIdx.x*256 + threadIdx.x;
  int tot2 = 35*512;
  if (i < tot2){
    int blk = i >> 9;
    int idx = i & 511;
    int hc = idx >> 3, w = idx & 7;
    const float* src; int WN, cb, u;
    if (blk < 3){ src=w2s; WN=24; cb=blk*8; u=0; }
    else if (blk < 15){ int b=blk-3; int p=b/3; u=b-p*3; src=w2p; WN=96; const int cbs[4]={0,24,48,72}; cb=cbs[p]; }
    else { int b=blk-15; int p=b/5; u=b-p*5; src=w2d; WN=160; const int cbs[4]={0,40,80,120}; cb=cbs[p]; }
    wr[i] = src[hc*WN + cb + u*8 + w];
  } else if (i < tot2 + 3*640){
    int r = i - tot2;
    int c = r/640; int rem = r - c*640;
    int chunk = rem/40; int idx = rem - chunk*40;
    int b = idx>>2, j = idx&3;
    const float* src = (c==0)? w1s : (c==1)? w1p : w1d;
    wr[i] = src[b*64 + chunk*4 + j];
  }
}

// ---------------------------------------------------------------------------
// CSR build: hist -> scan -> scatter  (sorted by destination node `col`)
// ---------------------------------------------------------------------------
__device__ __forceinline__ bool edge_ok(const float* __restrict__ pos, int row, int col, float mrf){
  float ax = pos[3*row+0]-pos[3*col+0];
  float ay = pos[3*row+1]-pos[3*col+1];
  float az = pos[3*row+2]-pos[3*col+2];
  float d  = sqrtf(fmaf(ax,ax, fmaf(ay,ay, fmaf(az,az, 1e-12f))));
  return d < mrf;
}

__global__ void hist_kernel(const int* __restrict__ ei, const float* __restrict__ pos,
                            const int* __restrict__ mrp, int* __restrict__ cnt, int E){
  int e = blockIdx.x*256 + threadIdx.x;
  if (e >= E) return;
  int row = ei[e], col = ei[E+e];
  if (edge_ok(pos,row,col,(float)mrp[0])) atomicAdd(&cnt[col], 1);
}

__device__ __forceinline__ int wscan(int v, int lane){
  #pragma unroll
  for (int s=1;s<64;s<<=1){
    int t = __shfl_up(v, s);
    if (lane >= s) v += t;
  }
  return v;
}

__global__ void scan_kernel(int* __restrict__ cnt, int* __restrict__ off, int N){
  __shared__ int wsum[16];
  __shared__ int srun;
  int t=threadIdx.x, lane=t&63, w=t>>6;
  if (t==0) srun=0;
  __syncthreads();
  for (int base=0; base<N; base+=1024){
    int v = (base+t<N) ? cnt[base+t] : 0;
    int incl = wscan(v, lane);
    if (lane==63) wsum[w]=incl;
    __syncthreads();
    int run = srun;
    int woff = 0;
    for (int i=0;i<w;i++) woff += wsum[i];
    int ex = run + woff + incl - v;
    if (base+t<N){ off[base+t]=ex; cnt[base+t]=ex; }
    __syncthreads();
    if (t==1023) srun = run + woff + incl;
    __syncthreads();
  }
  if (t==0) off[N]=srun;
}

__global__ void scatter_kernel(const int* __restrict__ ei, const float* __restrict__ pos,
                               const int* __restrict__ mrp, int* __restrict__ cursor,
                               int* __restrict__ csrR, int* __restrict__ csrC, int E){
  int e = blockIdx.x*256 + threadIdx.x;
  if (e >= E) return;
  int row = ei[e], col = ei[E+e];
  if (edge_ok(pos,row,col,(float)mrp[0])){
    int s = atomicAdd(&cursor[col], 1);
    csrR[s] = row;
    csrC[s] = col;
  }
}

// ---------------------------------------------------------------------------
// Edge compute helpers.  h in LDS (round-8 verified structure).
// All fmaf chain orders bit-identical to rounds 8/9.
// ---------------------------------------------------------------------------
// Packed-W1 compute_h: per chunk one contiguous 160B SMEM row.
// unroll 1: keeps ds_write_b128s spaced by the FMA chain (no paired-write
// LDS conflicts -- the round-9/12 5.9M-conflict trigger was unroll 2).
__device__ __forceinline__ void compute_h(const float (&emb)[10], const float* __restrict__ w1r, float* hrow){
  const float RS10 = 0.31622776601683794f;  // 1/sqrt(10)
  #pragma unroll 1
  for (int i=0; i<16; ++i){
    const float* r = w1r + i*40;
    float a0=0.f,a1=0.f,a2=0.f,a3=0.f;
    #pragma unroll
    for (int b=0;b<10;b++){
      a0 = fmaf(emb[b], r[b*4+0], a0);
      a1 = fmaf(emb[b], r[b*4+1], a1);
      a2 = fmaf(emb[b], r[b*4+2], a2);
      a3 = fmaf(emb[b], r[b*4+3], a3);
    }
    float4 hv;
    hv.x = fmaxf(a0*RS10, 0.f);
    hv.y = fmaxf(a1*RS10, 0.f);
    hv.z = fmaxf(a2*RS10, 0.f);
    hv.w = fmaxf(a3*RS10, 0.f);
    *reinterpret_cast<float4*>(hrow+i*4) = hv;
  }
}

// Raw-W1 compute_h (fallback kernel only).
__device__ __forceinline__ void compute_h_raw(const float (&emb)[10], const float* __restrict__ w1, float* hrow){
  const float RS10 = 0.31622776601683794f;
  #pragma unroll 1
  for (int hh=0; hh<64; hh+=4){
    float a0=0.f,a1=0.f,a2=0.f,a3=0.f;
    #pragma unroll
    for (int b=0;b<10;b++){
      const float* r = w1 + b*64 + hh;
      a0 = fmaf(emb[b], r[0], a0);
      a1 = fmaf(emb[b], r[1], a1);
      a2 = fmaf(emb[b], r[2], a2);
      a3 = fmaf(emb[b], r[3], a3);
    }
    float4 hv;
    hv.x = fmaxf(a0*RS10, 0.f);
    hv.y = fmaxf(a1*RS10, 0.f);
    hv.z = fmaxf(a2*RS10, 0.f);
    hv.w = fmaxf(a3*RS10, 0.f);
    *reinterpret_cast<float4*>(hrow+hh) = hv;
  }
}

// s[k] = CP * sum_{i,j} x1[i]*sh[j]*W3J[i,j,k]
template<int L1, int L2, int L3, int W3JOFF>
__device__ __forceinline__ void calc_s(const float* __restrict__ w3j,
    const float (&x1)[2*L1+1], const float (&sh1)[3], const float (&sh2)[5],
    float CP, float (&s)[2*L3+1])
{
  constexpr int N1=2*L1+1, N2=2*L2+1, N3=2*L3+1;
  #pragma unroll
  for (int k=0;k<N3;k++) s[k]=0.f;
  #pragma unroll
  for (int i=0;i<N1;i++){
    #pragma unroll
    for (int j=0;j<N2;j++){
      float shv = (L2==0) ? 1.0f : ((L2==1) ? sh1[j] : sh2[j]);
      float c = x1[i]*shv;
      #pragma unroll
      for (int k=0;k<N3;k++)
        s[k] = fmaf(c, w3j[W3JOFF + (i*N2+j)*N3 + k], s[k]);
    }
  }
  #pragma unroll
  for (int k=0;k<N3;k++) s[k] *= CP;
}

// Merged wg pass over REPACKED weights (round-8 verified: unroll 1, SMEM
// weight stream via uniform addresses, one ds_read_b128 of h per iteration).
template<int P>
__device__ __forceinline__ void wg_pass_r(const float* __restrict__ wr,
    const int (&blks)[P], const float* __restrict__ hrow, float (&wg)[P][8])
{
  #pragma unroll
  for (int p=0;p<P;p++)
    #pragma unroll
    for (int w=0;w<8;w++) wg[p][w]=0.f;
  #pragma unroll 1
  for (int hc=0;hc<64;hc+=4){
    float4 hv = *reinterpret_cast<const float4*>(hrow+hc);
    #pragma unroll
    for (int p=0;p<P;p++){
      const float* r0 = wr + blks[p]*512 + hc*8;
      #pragma unroll
      for (int w=0;w<8;w++){
        float t0 = fmaf(hv.x, r0[w],    wg[p][w]);
        t0       = fmaf(hv.y, r0[8+w],  t0);
        t0       = fmaf(hv.z, r0[16+w], t0);
        wg[p][w] = fmaf(hv.w, r0[24+w], t0);
      }
    }
  }
}

// Legacy merged wg pass over raw W2 (fallback kernel only).
template<int P, int WN>
__device__ __forceinline__ void wg_pass(const float* __restrict__ w2,
    const int (&cb)[P], int u8, const float* __restrict__ hrow, float (&wg)[P][8])
{
  #pragma unroll
  for (int p=0;p<P;p++)
    #pragma unroll
    for (int w=0;w<8;w++) wg[p][w]=0.f;
  #pragma unroll 1
  for (int hc=0;hc<64;hc+=4){
    float4 hv = *reinterpret_cast<const float4*>(hrow+hc);
    #pragma unroll
    for (int p=0;p<P;p++){
      const float* r0 = w2 + cb[p] + u8 + hc*WN;
      #pragma unroll
      for (int w=0;w<8;w++){
        float t0 = fmaf(hv.x, r0[w],      wg[p][w]);
        t0       = fmaf(hv.y, r0[WN+w],   t0);
        t0       = fmaf(hv.z, r0[2*WN+w], t0);
        wg[p][w] = fmaf(hv.w, r0[3*WN+w], t0);
      }
    }
  }
}

template<int N3, int OUTB>
__device__ __forceinline__ void acc_o(const float (&wgp)[8], const float (&s)[N3], float (&o)[72]){
  #pragma unroll
  for (int w=0;w<8;w++){
    #pragma unroll
    for (int k=0;k<N3;k++)
      o[OUTB + w*N3 + k] = fmaf(wgp[w], s[k], o[OUTB + w*N3 + k]);
  }
}

// ---------------------------------------------------------------------------
// CSR edge kernel: one thread per CSR slot; block-wide segmented reduction.
// ---------------------------------------------------------------------------
template<bool PACKED>
__global__ __launch_bounds__(BLK) void edge_kernel_csr(
  const int* __restrict__ csrR, const int* __restrict__ csrC,
  const int* __restrict__ off, int N,
  const float* __restrict__ pos, const float* __restrict__ x, const float* __restrict__ xp,
  const float* __restrict__ w3j, const int* __restrict__ mrp,
  const float* __restrict__ wr,
  float* __restrict__ out, float rs)
{
  __shared__ __align__(16) float hb[BLK*RSTR];  // per-thread h row / o staging
  __shared__ int scol[BLK];
  __shared__ int lmeta[BLK];   // s0 | len<<8 | comp<<31
  __shared__ int lcount;

  int tid = threadIdx.x;
  int blockBase = blockIdx.x*BLK;
  int Ev = off[N];
  if (blockBase >= Ev) return;
  int slot = blockBase + tid;
  bool valid = slot < Ev;
  int row = valid ? csrR[slot] : 0;
  int key = valid ? csrC[slot] : -1;
  int colIdx = valid ? key : 0;

  scol[tid] = key;
  if (tid==0) lcount = 0;
  __syncthreads();
  if (valid && (tid==0 || scol[tid-1]!=key)){
    int len=1;
    while (tid+len<BLK && scol[tid+len]==key) len++;
    int comp = (off[key] >= blockBase) && (off[key+1] <= blockBase+BLK);
    int idx = atomicAdd(&lcount, 1);
    lmeta[idx] = tid | (len<<8) | (comp<<31);
  }
  __syncthreads();
  int lc = lcount;

  // ---- geometry + radial embedding ----
  // Invalid lanes use row=col=0 -> d~1e-6 -> emb underflows to exactly 0 -> o = 0.
  float ax = pos[3*row+0]-pos[3*colIdx+0];
  float ay = pos[3*row+1]-pos[3*colIdx+1];
  float az = pos[3*row+2]-pos[3*colIdx+2];
  float d  = sqrtf(fmaf(ax,ax, fmaf(ay,ay, fmaf(az,az, 1e-12f))));
  float mrf = (float)mrp[0];
  float inv = 1.0f/d;
  float ux=ax*inv, uy=ay*inv, uz=az*inv;
  float sh1[3] = {1.7320508075688772f*uy, 1.7320508075688772f*uz, 1.7320508075688772f*ux};
  float sh2[5] = {3.872983346207417f*ux*uy, 3.872983346207417f*uy*uz,
                  1.118033988749895f*(3.f*uz*uz-1.f), 3.872983346207417f*ux*uz,
                  1.9364916731037085f*(ux*ux-uy*uy)};
  float emb[10];
  {
    float xs = d * (11.0f/mrf);
    float CE = 1.14136f * expf(2.0f) * sqrtf(10.0f);
    #pragma unroll
    for (int b=0;b<10;b++){
      float t1 = xs - (float)b;
      float t2 = (float)(b+2) - xs;
      float s1 = (t1>0.f)? expf(-1.0f/t1) : 0.f;
      float s2 = (t2>0.f)? expf(-1.0f/t2) : 0.f;
      emb[b] = CE*s1*s2;
    }
  }

  float* hrow = &hb[tid*RSTR];
  const float* xrow = PACKED ? (xp + (size_t)row*35) : (x + (size_t)row*162);
  const float* w1r = wr + W1OFF;

  auto flush_reduce = [&](const float (&o)[72], int PO){
    #pragma unroll
    for (int i=0;i<72;i+=4){
      float4 v; v.x=o[i]; v.y=o[i+1]; v.z=o[i+2]; v.w=o[i+3];
      *reinterpret_cast<float4*>(hrow+i) = v;
    }
    __syncthreads();
    int total = lc*72;
    for (int task = tid; task < total; task += BLK){
      int li = task/72;
      int el = task - li*72;
      int meta = lmeta[li];
      int s0  = meta & 255;
      int len = (meta>>8) & 255;
      int c   = scol[s0];
      float sum = 0.f;
      const float* p = &hb[s0*RSTR + el];
      for (int i=0;i<len;i++) sum += p[i*RSTR];
      float* dst = out + (size_t)c*216 + PO + el;
      if (meta < 0) *dst = sum;            // comp bit set: unique writer
      else unsafeAtomicAdd(dst, sum);      // block-boundary segment
    }
    __syncthreads();
  };

  // ---- l1 = 0 (s channel): 3 paths, one wg sweep ----
  {
    compute_h(emb, w1r + 0, hrow);
    float o[72];
    #pragma unroll
    for (int i=0;i<72;i++) o[i]=0.f;
    float x1[1];
    x1[0] = PACKED ? xrow[0] : (xrow[0]+xrow[1]);
    float sA[1], sB[3], sC[5];
    calc_s<0,0,0,  0>(w3j,x1,sh1,sh2, 0.17677669529663687f*rs, sA);
    calc_s<0,1,1,  1>(w3j,x1,sh1,sh2, 0.30618621784789724f*rs, sB);
    calc_s<0,2,2, 10>(w3j,x1,sh1,sh2, 0.39528470752104744f*rs, sC);
    float wg[3][8];
    const int blks[3] = {0,1,2};
    wg_pass_r<3>(wr, blks, hrow, wg);
    acc_o<1, 0>(wg[0], sA, o);
    acc_o<3, 8>(wg[1], sB, o);
    acc_o<5,32>(wg[2], sC, o);
    flush_reduce(o, 0);
  }
  // ---- l1 = 1 (p channel): 4 paths, one wg sweep per u ----
  {
    compute_h(emb, w1r + 640, hrow);
    float o[72];
    #pragma unroll
    for (int i=0;i<72;i++) o[i]=0.f;
    #pragma unroll 1
    for (int u=0;u<3;++u){
      float x1[3];
      #pragma unroll
      for (int i=0;i<3;i++){
        int src = ((1+u)*9 + 1+i)*2;
        x1[i] = PACKED ? xrow[1+u*3+i] : (xrow[src]+xrow[src+1]);
      }
      float sA[3], sB[1], sC[5], sD[3];
      calc_s<1,0,1, 35>(w3j,x1,sh1,sh2, 0.125f*rs,               sA);
      calc_s<1,1,0, 44>(w3j,x1,sh1,sh2, 0.10206207261596577f*rs, sB);
      calc_s<1,1,2, 53>(w3j,x1,sh1,sh2, 0.22821773229381923f*rs, sC);
      calc_s<1,2,1, 98>(w3j,x1,sh1,sh2, 0.125f*rs,               sD);
      float wg[4][8];
      const int blks[4] = {3+u, 6+u, 9+u, 12+u};
      wg_pass_r<4>(wr, blks, hrow, wg);
      acc_o<3, 8>(wg[0], sA, o);
      acc_o<1, 0>(wg[1], sB, o);
      acc_o<5,32>(wg[2], sC, o);
      acc_o<3, 8>(wg[3], sD, o);
    }
    flush_reduce(o, 72);
  }
  // ---- l1 = 2 (d channel): 4 paths, one wg sweep per u ----
  {
    compute_h(emb, w1r + 1280, hrow);
    float o[72];
    #pragma unroll
    for (int i=0;i<72;i++) o[i]=0.f;
    #pragma unroll 1
    for (int u=0;u<5;++u){
      float x1[5];
      #pragma unroll
      for (int i=0;i<5;i++){
        int src = ((4+u)*9 + 4+i)*2;
        x1[i] = PACKED ? xrow[10+u*5+i] : (xrow[src]+xrow[src+1]);
      }
      float sA[5], sB[3], sC[1], sD[5];
      calc_s<2,0,2,143>(w3j,x1,sh1,sh2, 0.125f*rs,               sA);
      calc_s<2,1,1,168>(w3j,x1,sh1,sh2, 0.13693063937629152f*rs, sB);
      calc_s<2,2,0,213>(w3j,x1,sh1,sh2, 0.07905694150420948f*rs, sC);
      calc_s<2,2,2,238>(w3j,x1,sh1,sh2, 0.125f*rs,               sD);
      float wg[4][8];
      const int blks[4] = {15+u, 20+u, 25+u, 30+u};
      wg_pass_r<4>(wr, blks, hrow, wg);
      acc_o<5,32>(wg[0], sA, o);
      acc_o<3, 8>(wg[1], sB, o);
      acc_o<1, 0>(wg[2], sC, o);
      acc_o<5,32>(wg[3], sD, o);
    }
    flush_reduce(o, 144);
  }
}

// ---------------------------------------------------------------------------
// Tier-C fallback: atomic kernel over raw W1/W2 (used only if workspace tiny)
// ---------------------------------------------------------------------------
__device__ __forceinline__ void flush72(const float (&o)[72], float* dst){
  #pragma unroll
  for (int i=0;i<72;i++) unsafeAtomicAdd(dst+i, o[i]);
}

__global__ __launch_bounds__(BLK) void edge_kernel_atomic(
  const int* __restrict__ ei, const float* __restrict__ pos,
  const float* __restrict__ x,
  const float* __restrict__ w3j, const int* __restrict__ mrp,
  const float* __restrict__ w1s, const float* __restrict__ w2s,
  const float* __restrict__ w1p, const float* __restrict__ w2p,
  const float* __restrict__ w1d, const float* __restrict__ w2d,
  float* __restrict__ out, int E, float rs)
{
  __shared__ __align__(16) float hbA[BLK*RSTR];
  int e = blockIdx.x*BLK + threadIdx.x;
  if (e >= E) return;
  int row = ei[e], col = ei[E+e];
  float ax = pos[3*row+0]-pos[3*col+0];
  float ay = pos[3*row+1]-pos[3*col+1];
  float az = pos[3*row+2]-pos[3*col+2];
  float d  = sqrtf(fmaf(ax,ax, fmaf(ay,ay, fmaf(az,az, 1e-12f))));
  float mrf = (float)mrp[0];
  if (d >= mrf) return;
  float inv = 1.0f/d;
  float ux=ax*inv, uy=ay*inv, uz=az*inv;
  float sh1[3] = {1.7320508075688772f*uy, 1.7320508075688772f*uz, 1.7320508075688772f*ux};
  float sh2[5] = {3.872983346207417f*ux*uy, 3.872983346207417f*uy*uz,
                  1.118033988749895f*(3.f*uz*uz-1.f), 3.872983346207417f*ux*uz,
                  1.9364916731037085f*(ux*ux-uy*uy)};
  float emb[10];
  {
    float xs = d * (11.0f/mrf);
    float CE = 1.14136f * expf(2.0f) * sqrtf(10.0f);
    #pragma unroll
    for (int b=0;b<10;b++){
      float t1 = xs - (float)b;
      float t2 = (float)(b+2) - xs;
      float s1 = (t1>0.f)? expf(-1.0f/t1) : 0.f;
      float s2 = (t2>0.f)? expf(-1.0f/t2) : 0.f;
      emb[b] = CE*s1*s2;
    }
  }
  float* hrow = &hbA[threadIdx.x*RSTR];
  const float* xrow = x + (size_t)row*162;
  float* obase = out + (size_t)col*216;
  {
    compute_h_raw(emb, w1s, hrow);
    float o[72];
    #pragma unroll
    for (int i=0;i<72;i++) o[i]=0.f;
    float x1[1] = { xrow[0]+xrow[1] };
    float sA[1], sB[3], sC[5];
    calc_s<0,0,0,  0>(w3j,x1,sh1,sh2, 0.17677669529663687f*rs, sA);
    calc_s<0,1,1,  1>(w3j,x1,sh1,sh2, 0.30618621784789724f*rs, sB);
    calc_s<0,2,2, 10>(w3j,x1,sh1,sh2, 0.39528470752104744f*rs, sC);
    float wg[3][8];
    const int cb[3] = {0,8,16};
    wg_pass<3,24>(w2s, cb, 0, hrow, wg);
    acc_o<1, 0>(wg[0], sA, o);
    acc_o<3, 8>(wg[1], sB, o);
    acc_o<5,32>(wg[2], sC, o);
    flush72(o, obase);
  }
  {
    compute_h_raw(emb, w1p, hrow);
    float o[72];
    #pragma unroll
    for (int i=0;i<72;i++) o[i]=0.f;
    #pragma unroll 1
    for (int u=0;u<3;++u){
      float x1[3];
      #pragma unroll
      for (int i=0;i<3;i++){ int src = ((1+u)*9 + 1+i)*2; x1[i] = xrow[src]+xrow[src+1]; }
      float sA[3], sB[1], sC[5], sD[3];
      calc_s<1,0,1, 35>(w3j,x1,sh1,sh2, 0.125f*rs,               sA);
      calc_s<1,1,0, 44>(w3j,x1,sh1,sh2, 0.10206207261596577f*rs, sB);
      calc_s<1,1,2, 53>(w3j,x1,sh1,sh2, 0.22821773229381923f*rs, sC);
      calc_s<1,2,1, 98>(w3j,x1,sh1,sh2, 0.125f*rs,               sD);
      float wg[4][8];
      const int cb[4] = {0,24,48,72};
      wg_pass<4,96>(w2p, cb, u*8, hrow, wg);
      acc_o<3, 8>(wg[0], sA, o);
      acc_o<1, 0>(wg[1], sB, o);
      acc_o<5,32>(wg[2], sC, o);
      acc_o<3, 8>(wg[3], sD, o);
    }
    flush72(o, obase + 72);
  }
  {
    compute_h_raw(emb, w1d, hrow);
    float o[72];
    #pragma unroll
    for (int i=0;i<72;i++) o[i]=0.f;
    #pragma unroll 1
    for (int u=0;u<5;++u){
      float x1[5];
      #pragma unroll
      for (int i=0;i<5;i++){ int src = ((4+u)*9 + 4+i)*2; x1[i] = xrow[src]+xrow[src+1]; }
      float sA[5], sB[3], sC[1], sD[5];
      calc_s<2,0,2,143>(w3j,x1,sh1,sh2, 0.125f*rs,               sA);
      calc_s<2,1,1,168>(w3j,x1,sh1,sh2, 0.13693063937629152f*rs, sB);
      calc_s<2,2,0,213>(w3j,x1,sh1,sh2, 0.07905694150420948f*rs, sC);
      calc_s<2,2,2,238>(w3j,x1,sh1,sh2, 0.125f*rs,               sD);
      float wg[4][8];
      const int cb[4] = {0,40,80,120};
      wg_pass<4,160>(w2d, cb, u*8, hrow, wg);
      acc_o<5,32>(wg[0], sA, o);
      acc_o<3, 8>(wg[1], sB, o);
      acc_o<1, 0>(wg[2], sC, o);
      acc_o<5,32>(wg[3], sD, o);
    }
    flush72(o, obase + 144);
  }
}

// ---------------------------------------------------------------------------
extern "C" void kernel_launch(void* const* d_in, const int* in_sizes, int n_in,
                              void* d_out, int out_size, void* d_ws, size_t ws_size,
                              hipStream_t stream){
  (void)n_in; (void)out_size;
  const float* x   = (const float*)d_in[0];
  const int*   ei  = (const int*)  d_in[1];
  const float* pos = (const float*)d_in[2];
  const int*   mr  = (const int*)  d_in[3];
  const float* w1s = (const float*)d_in[5];
  const float* w2s = (const float*)d_in[6];
  const float* w1p = (const float*)d_in[7];
  const float* w2p = (const float*)d_in[8];
  const float* w1d = (const float*)d_in[9];
  const float* w2d = (const float*)d_in[10];

  int N = in_sizes[0]/162;
  int E = in_sizes[1]/2;
  float rs = sqrtf((float)N/(float)E);

  auto alignup = [](size_t v){ return (v + 255) & ~(size_t)255; };
  size_t o_off  = 0;
  size_t o_cnt  = alignup(o_off + (size_t)(N+1)*4);
  size_t o_csrR = alignup(o_cnt + (size_t)N*4);
  size_t o_csrC = alignup(o_csrR + (size_t)E*4);
  size_t o_w3j  = alignup(o_csrC + (size_t)E*4);
  size_t o_wr   = alignup(o_w3j + 2048);
  size_t o_xp   = alignup(o_wr + (size_t)(35*512 + 3*640)*4);
  size_t needB  = o_xp;
  size_t needA  = o_xp + (size_t)N*35*4;

  char* wsb = (char*)d_ws;
  hipMemsetAsync(d_out, 0, (size_t)N*216*sizeof(float), stream);

  if (ws_size >= needB){
    int*   off  = (int*)(wsb + o_off);
    int*   cnt  = (int*)(wsb + o_cnt);
    int*   csrR = (int*)(wsb + o_csrR);
    int*   csrC = (int*)(wsb + o_csrC);
    float* w3j  = (float*)(wsb + o_w3j);
    float* wr   = (float*)(wsb + o_wr);
    float* xp   = (float*)(wsb + o_xp);

    hipMemsetAsync(cnt, 0, (size_t)N*4, stream);
    w3j_kernel<<<1,384,0,stream>>>(w3j);
    int rtot = 35*512 + 3*640;
    repack_kernel<<<(rtot+255)/256,256,0,stream>>>(w2s, w2p, w2d, w1s, w1p, w1d, wr);
    hist_kernel<<<(E+255)/256,256,0,stream>>>(ei, pos, mr, cnt, E);
    scan_kernel<<<1,1024,0,stream>>>(cnt, off, N);
    scatter_kernel<<<(E+255)/256,256,0,stream>>>(ei, pos, mr, cnt, csrR, csrC, E);

    int nblk = (E + BLK - 1)/BLK;
    if (ws_size >= needA){
      int tot = N*35;
      pack_kernel<<<(tot+255)/256,256,0,stream>>>(x, xp, tot);
      edge_kernel_csr<true><<<nblk, BLK, 0, stream>>>(
        csrR, csrC, off, N, pos, x, xp, w3j, mr, wr, (float*)d_out, rs);
    } else {
      edge_kernel_csr<false><<<nblk, BLK, 0, stream>>>(
        csrR, csrC, off, N, pos, x, x, w3j, mr, wr, (float*)d_out, rs);
    }
  } else {
    float* w3j = (float*)wsb;
    w3j_kernel<<<1,384,0,stream>>>(w3j);
    edge_kernel_atomic<<<(E+BLK-1)/BLK, BLK, 0, stream>>>(
      ei, pos, x, w3j, mr, w1s, w2s, w1p, w2p, w1d, w2d, (float*)d_out, E, rs);
  }
}